// Round 6
// baseline (568.679 us; speedup 1.0000x reference)
//
#include <hip/hip_runtime.h>
#include <hip/hip_cooperative_groups.h>

// ---------------------------------------------------------------------------
// LabelSimilarity: match[b,l] = max(-1, max_{s,v} cos(embed[s,b,:], label[l,v,:]))
// S=256 B=128 D=768 ; L=200 V=8 ; out [128,200] fp32
//
// R13: single cooperative-launch fused kernel. Evidence: across R7/R10/R11
// (three different tail structures) total-minus-gemm is constant ~127-144us
// while component arithmetic says ~40us -> fixed per-dispatch overhead (and
// an unobservable normalize) dominate the non-gemm time. One dispatch
// removes 3 launch/graph-node costs and grid.sync replaces kernel
// boundaries. Gemm main loop reverted to EXACT R7 (147us best; R8-R10
// pipeline grafts and R12 TLP both regressed -> structure is at its local
// ceiling). Grid = maxActiveBlocks*256 (LDS 32KB -> 1280 = 5/CU);
// 1280%8==0 preserves the XCD clustering decode (job j on block p==j mod
// 1280 -> p%8==j%8); per-CU gemm work = exactly 13 jobs, uniform.
// Fallback: if hipLaunchCooperativeKernel errors (capture/occupancy), run
// the proven R7 4-kernel path.
// ---------------------------------------------------------------------------

namespace cg = cooperative_groups;

typedef __bf16 bf16x8 __attribute__((ext_vector_type(8)));
typedef float  f32x4  __attribute__((ext_vector_type(4)));

#define GLD16(gp, lp) __builtin_amdgcn_global_load_lds(                        \
    (__attribute__((address_space(1))) void*)(gp),                             \
    (__attribute__((address_space(3))) void*)(lp), 16, 0, 0)

__device__ __forceinline__ unsigned short f32_to_bf16_rne(float x) {
  unsigned u = __float_as_uint(x);
  u += 0x7fffu + ((u >> 16) & 1u);
  return (unsigned short)(u >> 16);
}

// ---- phase helpers (shared by fused kernel and standalone fallback) -------

// One wave per row; rb = row-block index (4 rows per 256-thread block).
// rows [0,32768) -> embed->Ap ; rows [32768, 32768+1664) -> label->Bp
// (label rows >= 1600 are zero pad).
__device__ __forceinline__ void norm_rowblock(
    const float* __restrict__ embed, const float* __restrict__ label,
    unsigned short* __restrict__ Ap, unsigned short* __restrict__ Bp,
    int rb) {
  int row  = rb * 4 + (threadIdx.x >> 6);
  int lane = threadIdx.x & 63;
  const float* src;
  unsigned short* dstp;
  if (row < 32768) {
    src  = embed + (size_t)row * 768;
    dstp = Ap + (size_t)row * 768;
  } else {
    int lr = row - 32768;
    if (lr >= 1664) return;
    dstp = Bp + (size_t)lr * 768;
    if (lr >= 1600) {
      ushort4 z; z.x = z.y = z.z = z.w = 0;
      ushort4* drow = (ushort4*)dstp;
#pragma unroll
      for (int t = 0; t < 3; ++t) drow[lane + 64 * t] = z;
      return;
    }
    src = label + (size_t)lr * 768;
  }
  const float4* srow = (const float4*)src;
  ushort4* drow = (ushort4*)dstp;
  float4 v[3];
  float ss = 0.f;
#pragma unroll
  for (int t = 0; t < 3; ++t) {
    v[t] = srow[lane + 64 * t];
    ss += v[t].x * v[t].x + v[t].y * v[t].y + v[t].z * v[t].z + v[t].w * v[t].w;
  }
#pragma unroll
  for (int off = 1; off < 64; off <<= 1) ss += __shfl_xor(ss, off);
  float rinv = rsqrtf(fmaxf(ss, 1e-12f));
#pragma unroll
  for (int t = 0; t < 3; ++t) {
    ushort4 h;
    h.x = f32_to_bf16_rne(v[t].x * rinv);
    h.y = f32_to_bf16_rne(v[t].y * rinv);
    h.z = f32_to_bf16_rne(v[t].z * rinv);
    h.w = f32_to_bf16_rne(v[t].w * rinv);
    drow[lane + 64 * t] = h;
  }
}

// R7 GEMM job: 128x128 output tile, 2x16KB double-buffered LDS sets, one
// __syncthreads per K-iter. blk in [0,3328); XCD-clustered decode.
// Writes scratch[(bx*256+s)*2048 + b*16 + ll].
__device__ __forceinline__ void gemm_job(
    const unsigned short* __restrict__ Ap,   // [32768][768] bf16 (normalized)
    const unsigned short* __restrict__ Bp,   // [1664][768]  bf16 (normalized)
    float* __restrict__ scratch, char* smem, int blk) {
  const int t    = threadIdx.x;
  const int lane = t & 63;
  const int w    = t >> 6;             // wave 0..3

  // XCD-aware decode: blk -> (bx, s); the 13 A-tile sharers co-locate.
  const int xcd = blk & 7;
  const int idx = blk >> 3;            // 0..415
  const int bx  = idx % 13;
  const int s   = xcd * 32 + idx / 13;
  const int n0  = bx * 128;

  // staging: LDS slot == t (16B). slot (row=t>>2, cs=t&3) holds global chunk
  // cg = cs ^ ((row>>1)&3) (swizzle stays inside the row's 64B line).
  const int srow = t >> 2;
  const int cgc  = (t & 3) ^ ((t >> 3) & 3);
  const char* gA = (const char*)(Ap + (size_t)(s * 128) * 768);
  const char* gB = (const char*)(Bp + (size_t)n0 * 768);
  const char* ga0 = gA + srow * 1536 + cgc * 16;         // rows 0..63
  const char* ga1 = ga0 + 64 * 1536;                     // rows 64..127
  const char* gb0 = gB + srow * 1536 + cgc * 16;
  const char* gb1 = gb0 + 64 * 1536;
  const int lA0 = w * 1024;            // offsets within a 16 KB set
  const int lA1 = 4096 + w * 1024;
  const int lB0 = 8192 + w * 1024;
  const int lB1 = 12288 + w * 1024;

  // wave tile: 2x2 waves, each 64x64 = 4x4 MFMA tiles of 16x16
  const int wm  = (w >> 1) * 64;
  const int wn  = (w & 1) * 64;
  const int r16 = lane & 15;
  const int swz  = (((lane >> 4) ^ ((r16 >> 1) & 3)) * 16);   // bytes
  const int aoffB = (wm + r16) * 64 + swz;          // within set's A half
  const int boffB = 8192 + (wn + r16) * 64 + swz;   // within set's B half

  f32x4 acc[4][4];
#pragma unroll
  for (int i = 0; i < 4; ++i)
#pragma unroll
    for (int j = 0; j < 4; ++j)
      acc[i][j] = (f32x4){0.f, 0.f, 0.f, 0.f};

  // prologue: stage chunk 0 into set 0
  GLD16(ga0, smem + lA0); GLD16(ga1, smem + lA1);
  GLD16(gb0, smem + lB0); GLD16(gb1, smem + lB1);
  ga0 += 64; ga1 += 64; gb0 += 64; gb1 += 64;

  for (int kk = 0; kk < 24; ++kk) {    // K = 768 = 24 * 32
    __syncthreads();                   // drains chunk-kk loads (issued 1 iter ago)
    char* const Sc = smem + (kk & 1) * 16384;        // compute set
    if (kk < 23) {                     // prefetch chunk kk+1 into other set
      char* const Sp = smem + ((kk + 1) & 1) * 16384;
      GLD16(ga0, Sp + lA0); GLD16(ga1, Sp + lA1);
      GLD16(gb0, Sp + lB0); GLD16(gb1, Sp + lB1);
      ga0 += 64; ga1 += 64; gb0 += 64; gb1 += 64;
    }
    bf16x8 af[4], bfr[4];
#pragma unroll
    for (int i = 0; i < 4; ++i)
      af[i] = *(const bf16x8*)(Sc + aoffB + i * 1024);
#pragma unroll
    for (int j = 0; j < 4; ++j)
      bfr[j] = *(const bf16x8*)(Sc + boffB + j * 1024);
#pragma unroll
    for (int i = 0; i < 4; ++i)
#pragma unroll
      for (int j = 0; j < 4; ++j)
        acc[i][j] = __builtin_amdgcn_mfma_f32_16x16x32_bf16(
            af[i], bfr[j], acc[i][j], 0, 0, 0);
  }
  __syncthreads();                     // all ds_reads done before smem reuse

  // epilogue: acc is cos. C/D: col=lane&15, row=(lane>>4)*4+r.
  // max over v (col groups of 8) via shuffle; compact via LDS (stride 17),
  // then coalesced float4 stores to the block's private scratch tile.
  float* red = (float*)smem;           // [128][17] floats = 8704 B
  const int rowg  = lane >> 4;
  const int lbit  = (lane >> 3) & 1;
  const bool writer = (lane & 7) == 0;
#pragma unroll
  for (int i = 0; i < 4; ++i) {
#pragma unroll
    for (int j = 0; j < 4; ++j) {
#pragma unroll
      for (int r = 0; r < 4; ++r) {
        float vv = acc[i][j][r];
        vv = fmaxf(vv, __shfl_xor(vv, 1));
        vv = fmaxf(vv, __shfl_xor(vv, 2));
        vv = fmaxf(vv, __shfl_xor(vv, 4));
        if (writer) {
          int b  = wm + i * 16 + rowg * 4 + r;
          int ll = (wn >> 3) + j * 2 + lbit;
          red[b * 17 + ll] = vv;
        }
      }
    }
  }
  __syncthreads();
  {
    const int b  = t >> 1;
    const int l8 = (t & 1) * 8;
    float4 p0, p1;
    p0.x = red[b * 17 + l8 + 0]; p0.y = red[b * 17 + l8 + 1];
    p0.z = red[b * 17 + l8 + 2]; p0.w = red[b * 17 + l8 + 3];
    p1.x = red[b * 17 + l8 + 4]; p1.y = red[b * 17 + l8 + 5];
    p1.z = red[b * 17 + l8 + 6]; p1.w = red[b * 17 + l8 + 7];
    float4* gg = (float4*)(scratch + ((size_t)(bx * 256 + s)) * 2048 + t * 8);
    gg[0] = p0; gg[1] = p1;
  }
  __syncthreads();   // protect red[] from the NEXT job's prologue GLD16
}

// reduce1 job (bx, sg): folds s in [sg*8, sg*8+8) -> partial[bx][sg][2048]
__device__ __forceinline__ void reduce1_job(
    const float* __restrict__ scratch, float* __restrict__ partial,
    int bx, int sg) {
  const int t = threadIdx.x;
  const float* base = scratch + ((size_t)(bx * 256 + sg * 8)) * 2048 + t * 8;
  float4 m0 = ((const float4*)base)[0];
  float4 m1 = ((const float4*)base)[1];
  for (int ss = 1; ss < 8; ++ss) {
    const float4* p = (const float4*)(base + (size_t)ss * 2048);
    float4 a = p[0], b = p[1];
    m0.x = fmaxf(m0.x, a.x); m0.y = fmaxf(m0.y, a.y);
    m0.z = fmaxf(m0.z, a.z); m0.w = fmaxf(m0.w, a.w);
    m1.x = fmaxf(m1.x, b.x); m1.y = fmaxf(m1.y, b.y);
    m1.z = fmaxf(m1.z, b.z); m1.w = fmaxf(m1.w, b.w);
  }
  float4* o = (float4*)(partial + ((size_t)(bx * 32 + sg)) * 2048 + t * 8);
  o[0] = m0; o[1] = m1;
}

// reduce2 job: out[b][l] = max(-1, max over 32 partials)
__device__ __forceinline__ void reduce2_job(
    const float* __restrict__ partial, float* __restrict__ out, int job) {
  int idx = job * 256 + threadIdx.x;   // 0 .. 26623
  if (idx >= 13 * 2048) return;
  int bx = idx >> 11;
  int e  = idx & 2047;
  int b  = e >> 4;
  int ll = e & 15;
  int l  = bx * 16 + ll;
  if (l >= 200) return;
  float m = -1.0f;
  const float* p = partial + (size_t)(bx * 32) * 2048 + e;
  for (int c = 0; c < 32; ++c) m = fmaxf(m, p[(size_t)c * 2048]);
  out[b * 200 + l] = m;
}

// ---- fused cooperative kernel ---------------------------------------------
__global__ void __launch_bounds__(256) fused_all(
    const float* embed, const float* label, unsigned short* Ap,
    unsigned short* Bp, float* scratch, float* partial, float* out) {
  __shared__ char smem[32768];
  cg::grid_group grid = cg::this_grid();

  for (int rb = blockIdx.x; rb < 8608; rb += gridDim.x)
    norm_rowblock(embed, label, Ap, Bp, rb);
  __threadfence();
  grid.sync();

  for (int blk = blockIdx.x; blk < 3328; blk += gridDim.x)
    gemm_job(Ap, Bp, scratch, smem, blk);
  __threadfence();
  grid.sync();

  for (int j = blockIdx.x; j < 416; j += gridDim.x)
    reduce1_job(scratch, partial, j % 13, j / 13);
  __threadfence();
  grid.sync();

  for (int j = blockIdx.x; j < 104; j += gridDim.x)
    reduce2_job(partial, out, j);
}

// ---- standalone fallback kernels (exact R7 path) --------------------------
__global__ void __launch_bounds__(256) normalize_all(
    const float* __restrict__ embed, const float* __restrict__ label,
    unsigned short* __restrict__ Ap, unsigned short* __restrict__ Bp) {
  norm_rowblock(embed, label, Ap, Bp, blockIdx.x);
}

__global__ void __launch_bounds__(256) gemm_store_kernel(
    const unsigned short* __restrict__ Ap,
    const unsigned short* __restrict__ Bp,
    float* __restrict__ scratch) {
  __shared__ char smem[32768];
  gemm_job(Ap, Bp, scratch, smem, blockIdx.x);
}

__global__ void __launch_bounds__(256) reduce1_kernel(
    const float* __restrict__ scratch, float* __restrict__ partial) {
  reduce1_job(scratch, partial, blockIdx.x, blockIdx.y);
}

__global__ void __launch_bounds__(256) reduce2_kernel(
    const float* __restrict__ partial, float* __restrict__ out) {
  reduce2_job(partial, out, blockIdx.x);
}

// Brute-force fp32 fallback (only if ws_size is too small): one block per (b,l).
__global__ void __launch_bounds__(256) fallback_kernel(
    const float* __restrict__ embed, const float* __restrict__ label,
    float* __restrict__ out) {
  int b = blockIdx.x, l = blockIdx.y, t = threadIdx.x;
  float m = -1.0f;
  for (int p = t; p < 2048; p += 256) {
    int s = p >> 3, v = p & 7;
    const float* e = embed + (size_t)(s * 128 + b) * 768;
    const float* q = label + (size_t)(l * 8 + v) * 768;
    float dot = 0.f, ne = 0.f, nl = 0.f;
    for (int d = 0; d < 768; ++d) {
      float x = e[d], y = q[d];
      dot += x * y; ne += x * x; nl += y * y;
    }
    m = fmaxf(m, dot / fmaxf(sqrtf(ne) * sqrtf(nl), 1e-8f));
  }
  for (int off = 1; off < 64; off <<= 1) m = fmaxf(m, __shfl_xor(m, off));
  __shared__ float wmax[4];
  if ((t & 63) == 0) wmax[t >> 6] = m;
  __syncthreads();
  if (t == 0)
    out[b * 200 + l] = fmaxf(fmaxf(wmax[0], wmax[1]), fmaxf(wmax[2], wmax[3]));
}

extern "C" void kernel_launch(void* const* d_in, const int* in_sizes, int n_in,
                              void* d_out, int out_size, void* d_ws, size_t ws_size,
                              hipStream_t stream) {
  const float* embed = (const float*)d_in[0];   // [256,128,768]
  const float* label = (const float*)d_in[1];   // [200,8,768]
  float* out = (float*)d_out;                   // [128,200]

  const size_t szA = (size_t)32768 * 768 * 2;        // 50,331,648
  const size_t szB = (size_t)1664 * 768 * 2;         //  2,555,904
  const size_t szS = (size_t)13 * 256 * 2048 * 4;    // 27,262,976
  const size_t szP = (size_t)13 * 32 * 2048 * 4;     //  3,407,872

  if (ws_size < szA + szB + szS + szP) {
    dim3 g(128, 200);
    fallback_kernel<<<g, 256, 0, stream>>>(embed, label, out);
    return;
  }

  unsigned short* Ap = (unsigned short*)d_ws;
  unsigned short* Bp = (unsigned short*)((char*)d_ws + szA);
  float* scratch     = (float*)((char*)d_ws + szA + szB);
  float* partial     = (float*)((char*)d_ws + szA + szB + szS);

  // Try the single-dispatch cooperative path.
  int maxB = 0;
  hipError_t qe = hipOccupancyMaxActiveBlocksPerMultiprocessor(
      &maxB, fused_all, 256, 0);
  if (qe == hipSuccess && maxB > 0) {
    int grid = maxB * 256;             // 256 CUs; multiple of 8 -> XCD decode ok
    if (grid > 3328) grid = 3328;      // never more blocks than gemm jobs
    void* args[] = {(void*)&embed, (void*)&label, (void*)&Ap, (void*)&Bp,
                    (void*)&scratch, (void*)&partial, (void*)&out};
    hipError_t le = hipLaunchCooperativeKernel(
        fused_all, dim3(grid), dim3(256), args, 0, stream);
    if (le == hipSuccess) return;
  }

  // Fallback: proven R7 4-kernel path.
  normalize_all<<<8608, 256, 0, stream>>>(embed, label, Ap, Bp);
  gemm_store_kernel<<<3328, 256, 0, stream>>>(Ap, Bp, scratch);
  dim3 r1(13, 32);
  reduce1_kernel<<<r1, 256, 0, stream>>>(scratch, partial);
  reduce2_kernel<<<104, 256, 0, stream>>>(partial, out);
}

// Round 7
// 304.423 us; speedup vs baseline: 1.8681x; 1.8681x over previous
//
#include <hip/hip_runtime.h>

// ---------------------------------------------------------------------------
// LabelSimilarity: match[b,l] = max(-1, max_{s,v} cos(embed[s,b,:], label[l,v,:]))
// S=256 B=128 D=768 ; L=200 V=8 ; out [128,200] fp32
//
// R14: gemm = EXACT R7 (147us; R8-R13 structural experiments all regressed:
// counted-vmcnt pipelines -> races/occupancy loss; smaller tile -> more
// occupancy, same time (R12: residency-insensitive); cooperative fusion ->
// 2 blocks/CU serialization, 568us). Tail attack instead, where total-gemm
// is ~130us vs ~40us of BW floors:
//   (a) normalize: grid 2048 + grid-stride over 8608 row-blocks (G11: huge
//       grids of trivial blocks can be CP dispatch-rate-limited).
//   (b) reduce1+reduce2 merged into ONE kernel (13x16 blocks; two
//       128-thread s-halves, LDS combine) -- one less launch, less traffic.
// 3 launches total. XCD clustering (R6), XOR swizzles (R2) kept.
// ---------------------------------------------------------------------------

typedef __bf16 bf16x8 __attribute__((ext_vector_type(8)));
typedef float  f32x4  __attribute__((ext_vector_type(4)));

#define GLD16(gp, lp) __builtin_amdgcn_global_load_lds(                        \
    (__attribute__((address_space(1))) void*)(gp),                             \
    (__attribute__((address_space(3))) void*)(lp), 16, 0, 0)

__device__ __forceinline__ unsigned short f32_to_bf16_rne(float x) {
  unsigned u = __float_as_uint(x);
  u += 0x7fffu + ((u >> 16) & 1u);
  return (unsigned short)(u >> 16);
}

// One wave per row; grid-stride over 8608 row-blocks (4 rows each).
// rows [0,32768) -> embed->Ap ; rows [32768, 32768+1664) -> label->Bp
// (label rows >= 1600 are zero pad).
__global__ void __launch_bounds__(256) normalize_all(
    const float* __restrict__ embed, const float* __restrict__ label,
    unsigned short* __restrict__ Ap, unsigned short* __restrict__ Bp) {
  for (int rb = blockIdx.x; rb < 8608; rb += gridDim.x) {
    int row  = rb * 4 + (threadIdx.x >> 6);
    int lane = threadIdx.x & 63;
    const float* src;
    unsigned short* dstp;
    if (row < 32768) {
      src  = embed + (size_t)row * 768;
      dstp = Ap + (size_t)row * 768;
    } else {
      int lr = row - 32768;
      if (lr >= 1664) continue;
      dstp = Bp + (size_t)lr * 768;
      if (lr >= 1600) {
        ushort4 z; z.x = z.y = z.z = z.w = 0;
        ushort4* drow = (ushort4*)dstp;
#pragma unroll
        for (int t = 0; t < 3; ++t) drow[lane + 64 * t] = z;
        continue;
      }
      src = label + (size_t)lr * 768;
    }
    const float4* srow = (const float4*)src;
    ushort4* drow = (ushort4*)dstp;
    float4 v[3];
    float ss = 0.f;
#pragma unroll
    for (int t = 0; t < 3; ++t) {
      v[t] = srow[lane + 64 * t];
      ss += v[t].x * v[t].x + v[t].y * v[t].y + v[t].z * v[t].z + v[t].w * v[t].w;
    }
#pragma unroll
    for (int off = 1; off < 64; off <<= 1) ss += __shfl_xor(ss, off);
    float rinv = rsqrtf(fmaxf(ss, 1e-12f));
#pragma unroll
    for (int t = 0; t < 3; ++t) {
      ushort4 h;
      h.x = f32_to_bf16_rne(v[t].x * rinv);
      h.y = f32_to_bf16_rne(v[t].y * rinv);
      h.z = f32_to_bf16_rne(v[t].z * rinv);
      h.w = f32_to_bf16_rne(v[t].w * rinv);
      drow[lane + 64 * t] = h;
    }
  }
}

// GEMM + per-block max tile (EXACT R7). 1-D grid 3328; XCD-clustered.
// Writes scratch[(bx*256+s)*2048 + b*16 + ll].
__global__ void __launch_bounds__(256) gemm_store_kernel(
    const unsigned short* __restrict__ Ap,   // [32768][768] bf16 (normalized)
    const unsigned short* __restrict__ Bp,   // [1664][768]  bf16 (normalized)
    float* __restrict__ scratch) {
  __shared__ char smem[32768];   // set0: A[0,8K) B[8K,16K) ; set1: +16K

  const int t    = threadIdx.x;
  const int lane = t & 63;
  const int w    = t >> 6;             // wave 0..3

  // XCD-aware decode: blk -> (bx, s); the 13 A-tile sharers co-locate.
  const int blk = blockIdx.x;          // 0..3327
  const int xcd = blk & 7;
  const int idx = blk >> 3;            // 0..415
  const int bx  = idx % 13;
  const int s   = xcd * 32 + idx / 13;
  const int n0  = bx * 128;

  // staging: LDS slot == t (16B). slot (row=t>>2, cs=t&3) holds global chunk
  // cg = cs ^ ((row>>1)&3) (swizzle stays inside the row's 64B line).
  const int srow = t >> 2;
  const int cg   = (t & 3) ^ ((t >> 3) & 3);
  const char* gA = (const char*)(Ap + (size_t)(s * 128) * 768);
  const char* gB = (const char*)(Bp + (size_t)n0 * 768);
  const char* ga0 = gA + srow * 1536 + cg * 16;          // rows 0..63
  const char* ga1 = ga0 + 64 * 1536;                     // rows 64..127
  const char* gb0 = gB + srow * 1536 + cg * 16;
  const char* gb1 = gb0 + 64 * 1536;
  const int lA0 = w * 1024;            // offsets within a 16 KB set
  const int lA1 = 4096 + w * 1024;
  const int lB0 = 8192 + w * 1024;
  const int lB1 = 12288 + w * 1024;

  // wave tile: 2x2 waves, each 64x64 = 4x4 MFMA tiles of 16x16
  const int wm  = (w >> 1) * 64;
  const int wn  = (w & 1) * 64;
  const int r16 = lane & 15;
  const int swz  = (((lane >> 4) ^ ((r16 >> 1) & 3)) * 16);   // bytes
  const int aoffB = (wm + r16) * 64 + swz;          // within set's A half
  const int boffB = 8192 + (wn + r16) * 64 + swz;   // within set's B half

  f32x4 acc[4][4];
#pragma unroll
  for (int i = 0; i < 4; ++i)
#pragma unroll
    for (int j = 0; j < 4; ++j)
      acc[i][j] = (f32x4){0.f, 0.f, 0.f, 0.f};

  // prologue: stage chunk 0 into set 0
  GLD16(ga0, smem + lA0); GLD16(ga1, smem + lA1);
  GLD16(gb0, smem + lB0); GLD16(gb1, smem + lB1);
  ga0 += 64; ga1 += 64; gb0 += 64; gb1 += 64;

  for (int kk = 0; kk < 24; ++kk) {    // K = 768 = 24 * 32
    __syncthreads();                   // drains chunk-kk loads (issued 1 iter ago)
    char* const Sc = smem + (kk & 1) * 16384;        // compute set
    if (kk < 23) {                     // prefetch chunk kk+1 into other set
      char* const Sp = smem + ((kk + 1) & 1) * 16384;
      GLD16(ga0, Sp + lA0); GLD16(ga1, Sp + lA1);
      GLD16(gb0, Sp + lB0); GLD16(gb1, Sp + lB1);
      ga0 += 64; ga1 += 64; gb0 += 64; gb1 += 64;
    }
    bf16x8 af[4], bfr[4];
#pragma unroll
    for (int i = 0; i < 4; ++i)
      af[i] = *(const bf16x8*)(Sc + aoffB + i * 1024);
#pragma unroll
    for (int j = 0; j < 4; ++j)
      bfr[j] = *(const bf16x8*)(Sc + boffB + j * 1024);
#pragma unroll
    for (int i = 0; i < 4; ++i)
#pragma unroll
      for (int j = 0; j < 4; ++j)
        acc[i][j] = __builtin_amdgcn_mfma_f32_16x16x32_bf16(
            af[i], bfr[j], acc[i][j], 0, 0, 0);
  }
  __syncthreads();                     // all ds_reads done before smem reuse

  // epilogue: acc is cos. C/D: col=lane&15, row=(lane>>4)*4+r.
  // max over v (col groups of 8) via shuffle; compact via LDS (stride 17),
  // then coalesced float4 stores to the block's private scratch tile.
  float* red = (float*)smem;           // [128][17] floats = 8704 B
  const int rowg  = lane >> 4;
  const int lbit  = (lane >> 3) & 1;
  const bool writer = (lane & 7) == 0;
#pragma unroll
  for (int i = 0; i < 4; ++i) {
#pragma unroll
    for (int j = 0; j < 4; ++j) {
#pragma unroll
      for (int r = 0; r < 4; ++r) {
        float vv = acc[i][j][r];
        vv = fmaxf(vv, __shfl_xor(vv, 1));
        vv = fmaxf(vv, __shfl_xor(vv, 2));
        vv = fmaxf(vv, __shfl_xor(vv, 4));
        if (writer) {
          int b  = wm + i * 16 + rowg * 4 + r;
          int ll = (wn >> 3) + j * 2 + lbit;
          red[b * 17 + ll] = vv;
        }
      }
    }
  }
  __syncthreads();
  {
    const int b  = t >> 1;
    const int l8 = (t & 1) * 8;
    float4 p0, p1;
    p0.x = red[b * 17 + l8 + 0]; p0.y = red[b * 17 + l8 + 1];
    p0.z = red[b * 17 + l8 + 2]; p0.w = red[b * 17 + l8 + 3];
    p1.x = red[b * 17 + l8 + 4]; p1.y = red[b * 17 + l8 + 5];
    p1.z = red[b * 17 + l8 + 6]; p1.w = red[b * 17 + l8 + 7];
    float4* gg = (float4*)(scratch + ((size_t)(bx * 256 + s)) * 2048 + t * 8);
    gg[0] = p0; gg[1] = p1;
  }
}

// Single reduce: block (bx, p) covers e in [p*128, p*128+128).
// Threads 0-127 fold s in [0,128), threads 128-255 fold s in [128,256);
// halves combined via LDS. out[b][l] = max(-1, max_s scratch[bx,s,e]).
__global__ void __launch_bounds__(256) reduce_kernel(
    const float* __restrict__ scratch, float* __restrict__ out) {
  __shared__ float red2[128];
  const int t    = threadIdx.x;
  const int bx   = blockIdx.x;          // 0..12
  const int p    = blockIdx.y;          // 0..15
  const int half = t >> 7;              // 0 or 1
  const int eo   = t & 127;
  const int e    = p * 128 + eo;
  const float* base = scratch + ((size_t)(bx * 256 + half * 128)) * 2048 + e;
  float m = -1.0f;
#pragma unroll 8
  for (int ss = 0; ss < 128; ++ss)
    m = fmaxf(m, base[(size_t)ss * 2048]);
  if (half == 1) red2[eo] = m;
  __syncthreads();
  if (half == 0) {
    m = fmaxf(m, red2[eo]);
    int b  = e >> 4;
    int l  = bx * 16 + (e & 15);
    if (l < 200) out[b * 200 + l] = m;
  }
}

// Brute-force fp32 fallback (only if ws_size is too small): one block per (b,l).
__global__ void __launch_bounds__(256) fallback_kernel(
    const float* __restrict__ embed, const float* __restrict__ label,
    float* __restrict__ out) {
  int b = blockIdx.x, l = blockIdx.y, t = threadIdx.x;
  float m = -1.0f;
  for (int p = t; p < 2048; p += 256) {
    int s = p >> 3, v = p & 7;
    const float* e = embed + (size_t)(s * 128 + b) * 768;
    const float* q = label + (size_t)(l * 8 + v) * 768;
    float dot = 0.f, ne = 0.f, nl = 0.f;
    for (int d = 0; d < 768; ++d) {
      float x = e[d], y = q[d];
      dot += x * y; ne += x * x; nl += y * y;
    }
    m = fmaxf(m, dot / fmaxf(sqrtf(ne) * sqrtf(nl), 1e-8f));
  }
  for (int off = 1; off < 64; off <<= 1) m = fmaxf(m, __shfl_xor(m, off));
  __shared__ float wmax[4];
  if ((t & 63) == 0) wmax[t >> 6] = m;
  __syncthreads();
  if (t == 0)
    out[b * 200 + l] = fmaxf(fmaxf(wmax[0], wmax[1]), fmaxf(wmax[2], wmax[3]));
}

extern "C" void kernel_launch(void* const* d_in, const int* in_sizes, int n_in,
                              void* d_out, int out_size, void* d_ws, size_t ws_size,
                              hipStream_t stream) {
  const float* embed = (const float*)d_in[0];   // [256,128,768]
  const float* label = (const float*)d_in[1];   // [200,8,768]
  float* out = (float*)d_out;                   // [128,200]

  const size_t szA = (size_t)32768 * 768 * 2;        // 50,331,648
  const size_t szB = (size_t)1664 * 768 * 2;         //  2,555,904
  const size_t szS = (size_t)13 * 256 * 2048 * 4;    // 27,262,976

  if (ws_size < szA + szB + szS) {
    dim3 g(128, 200);
    fallback_kernel<<<g, 256, 0, stream>>>(embed, label, out);
    return;
  }

  unsigned short* Ap = (unsigned short*)d_ws;
  unsigned short* Bp = (unsigned short*)((char*)d_ws + szA);
  float* scratch     = (float*)((char*)d_ws + szA + szB);

  normalize_all<<<2048, 256, 0, stream>>>(embed, label, Ap, Bp);
  gemm_store_kernel<<<3328, 256, 0, stream>>>(Ap, Bp, scratch);
  dim3 r(13, 16);
  reduce_kernel<<<r, 256, 0, stream>>>(scratch, out);
}